// Round 1
// baseline (115.227 us; speedup 1.0000x reference)
//
#include <hip/hip_runtime.h>

#define B_TOT 2048
#define NTOK 64
#define DHEAD 32
#define NHEAD 3

// ---------------------------------------------------------------------------
// Bias MLP precompute: bias[h][n][m] = relu(rp(n,m) @ w1 + b1) @ w2 + b2
// rp(n,m) = sign(d)*log1p(|d|) for d = (n//8 - m//8, n%8 - m%8)
// 4096 (n,m) pairs, 3 heads -> 48 KB into workspace.
// ---------------------------------------------------------------------------
__global__ __launch_bounds__(256) void bias_kernel(const float* __restrict__ w1,
                                                   const float* __restrict__ b1,
                                                   const float* __restrict__ w2,
                                                   const float* __restrict__ b2,
                                                   float* __restrict__ bias) {
    int t = blockIdx.x * 256 + threadIdx.x;   // 0..4095
    int n = t >> 6, m = t & 63;
    float d0 = (float)((n >> 3) - (m >> 3));
    float d1 = (float)((n & 7) - (m & 7));
    float r0 = (d0 > 0.f ? 1.f : (d0 < 0.f ? -1.f : 0.f)) * log1pf(fabsf(d0));
    float r1 = (d1 > 0.f ? 1.f : (d1 < 0.f ? -1.f : 0.f)) * log1pf(fabsf(d1));
    float a0 = 0.f, a1 = 0.f, a2 = 0.f;
    for (int j = 0; j < 256; j++) {
        float hd = fmaf(r0, w1[j], fmaf(r1, w1[256 + j], b1[j]));
        hd = fmaxf(hd, 0.f);
        a0 = fmaf(hd, w2[j * 3 + 0], a0);
        a1 = fmaf(hd, w2[j * 3 + 1], a1);
        a2 = fmaf(hd, w2[j * 3 + 2], a2);
    }
    bias[0 * 4096 + n * 64 + m] = a0 + b2[0];
    bias[1 * 4096 + n * 64 + m] = a1 + b2[1];
    bias[2 * 4096 + n * 64 + m] = a2 + b2[2];
}

// ---------------------------------------------------------------------------
// Main kernel: one block per (b, h). 256 threads = 4 waves.
// Stages: load -> 8x8 cyclic conv (per channel) -> attn logits + softmax -> PV
// ---------------------------------------------------------------------------
__global__ __launch_bounds__(256, 3) void attn_kernel(const float* __restrict__ qkv,
                                                      const float* __restrict__ bias,
                                                      float* __restrict__ out) {
    __shared__ float q_r[64][32];   // [n][d] row-major
    __shared__ float k_r[64][32];
    __shared__ float v_t[32][68];   // [d][m] transposed, padded
    __shared__ float o_t[32][68];   // conv output transposed [d][n]; reused as x staging
    __shared__ float p[64][68];     // softmax probs [n][m], padded

    const int t = threadIdx.x;
    const int bh = blockIdx.x;
    const int b = bh / 3, h = bh % 3;
    const float scale = 0.17677669529663687f;  // 32^-0.5

    const float* base = qkv + (size_t)b * (NTOK * 288) + h * 32;

    // ---- load: fully coalesced float4, write q/k row-major, v transposed ----
    #pragma unroll
    for (int s = 0; s < 2; s++) {
        int e = t + 256 * s;          // 0..511
        int n = e >> 3, d0 = (e & 7) * 4;
        float4 q4 = *(const float4*)(base + n * 288 + 0 + d0);
        float4 k4 = *(const float4*)(base + n * 288 + 96 + d0);
        float4 v4 = *(const float4*)(base + n * 288 + 192 + d0);
        q4.x *= scale; q4.y *= scale; q4.z *= scale; q4.w *= scale;
        *(float4*)&q_r[n][d0] = q4;
        *(float4*)&k_r[n][d0] = k4;
        v_t[d0 + 0][n] = v4.x;
        v_t[d0 + 1][n] = v4.y;
        v_t[d0 + 2][n] = v4.z;
        v_t[d0 + 3][n] = v4.w;
    }
    __syncthreads();

    // ---- stage 1: 8x8 cyclic convolution per channel ----
    // thread owns (dd = t&31, y = t>>5); outputs out[y*8+x][dd], x=0..7
    {
        const int dd = t & 31, y = t >> 5;
        float acc[8];
        #pragma unroll
        for (int x = 0; x < 8; x++) acc[x] = 0.f;
        for (int u = 0; u < 8; u++) {
            const int yy = (y - u) & 7;
            float krow[8];
            #pragma unroll
            for (int xx = 0; xx < 8; xx++) krow[xx] = k_r[yy * 8 + xx][dd];
            #pragma unroll
            for (int v = 0; v < 8; v++) {
                float qv = q_r[u * 8 + v][dd];
                #pragma unroll
                for (int x = 0; x < 8; x++)
                    acc[x] = fmaf(qv, krow[(x - v) & 7], acc[x]);
            }
        }
        #pragma unroll
        for (int x = 0; x < 8; x++) o_t[dd][y * 8 + x] = acc[x];
    }
    __syncthreads();

    // ---- stage 2: attn logits (out @ v^T) + bias, in-register softmax ----
    // thread owns 4x4 tile: rows n0..n0+3, cols m0..m0+3
    {
        const int n0 = (t >> 4) * 4, m0 = (t & 15) * 4;
        float acc[4][4];
        #pragma unroll
        for (int i = 0; i < 4; i++)
            #pragma unroll
            for (int j = 0; j < 4; j++) acc[i][j] = 0.f;

        for (int dd = 0; dd < 32; dd++) {
            float4 o4 = *(const float4*)&o_t[dd][n0];
            float4 v4 = *(const float4*)&v_t[dd][m0];
            float oo[4] = {o4.x, o4.y, o4.z, o4.w};
            float vv[4] = {v4.x, v4.y, v4.z, v4.w};
            #pragma unroll
            for (int i = 0; i < 4; i++)
                #pragma unroll
                for (int j = 0; j < 4; j++)
                    acc[i][j] = fmaf(oo[i], vv[j], acc[i][j]);
        }
        // add bias
        const float* bb = bias + h * 4096;
        #pragma unroll
        for (int i = 0; i < 4; i++) {
            float4 b4 = *(const float4*)(bb + (n0 + i) * 64 + m0);
            acc[i][0] += b4.x; acc[i][1] += b4.y; acc[i][2] += b4.z; acc[i][3] += b4.w;
        }
        // softmax across the 16-lane group that shares this row block
        #pragma unroll
        for (int i = 0; i < 4; i++) {
            float mx = fmaxf(fmaxf(acc[i][0], acc[i][1]), fmaxf(acc[i][2], acc[i][3]));
            #pragma unroll
            for (int off = 1; off < 16; off <<= 1)
                mx = fmaxf(mx, __shfl_xor(mx, off, 64));
            float s = 0.f;
            #pragma unroll
            for (int j = 0; j < 4; j++) {
                acc[i][j] = __expf(acc[i][j] - mx);
                s += acc[i][j];
            }
            #pragma unroll
            for (int off = 1; off < 16; off <<= 1)
                s += __shfl_xor(s, off, 64);
            float r = 1.f / s;
            float4 p4 = {acc[i][0] * r, acc[i][1] * r, acc[i][2] * r, acc[i][3] * r};
            *(float4*)&p[n0 + i][m0] = p4;
        }
    }
    __syncthreads();

    // ---- stage 3: x = p @ v  (64x32x64), 128 threads, 4x4 tiles ----
    // thread (r = t&15, dg = t>>4 in 0..7) owns rows {r+16i}, channels {dg+8j}
    if (t < 128) {
        const int r = t & 15, dg = t >> 4;
        float acc[4][4];
        #pragma unroll
        for (int i = 0; i < 4; i++)
            #pragma unroll
            for (int j = 0; j < 4; j++) acc[i][j] = 0.f;

        for (int m0 = 0; m0 < 64; m0 += 4) {
            float4 pv[4];
            #pragma unroll
            for (int i = 0; i < 4; i++) pv[i] = *(const float4*)&p[r + 16 * i][m0];
            #pragma unroll
            for (int j = 0; j < 4; j++) {
                float4 vv = *(const float4*)&v_t[dg + 8 * j][m0];
                #pragma unroll
                for (int i = 0; i < 4; i++) {
                    acc[i][j] = fmaf(pv[i].x, vv.x, acc[i][j]);
                    acc[i][j] = fmaf(pv[i].y, vv.y, acc[i][j]);
                    acc[i][j] = fmaf(pv[i].z, vv.z, acc[i][j]);
                    acc[i][j] = fmaf(pv[i].w, vv.w, acc[i][j]);
                }
            }
        }
        // stage x transposed into o_t (dead after stage 2): x_t[dd][n]
        #pragma unroll
        for (int i = 0; i < 4; i++)
            #pragma unroll
            for (int j = 0; j < 4; j++)
                o_t[dg + 8 * j][r + 16 * i] = acc[i][j];
    }
    __syncthreads();

    // ---- store: out[b][n][h*32 + dd], coalesced float4 ----
    #pragma unroll
    for (int s = 0; s < 2; s++) {
        int e = t + 256 * s;
        int n = e >> 3, d0 = (e & 7) * 4;
        float4 x4;
        x4.x = o_t[d0 + 0][n];
        x4.y = o_t[d0 + 1][n];
        x4.z = o_t[d0 + 2][n];
        x4.w = o_t[d0 + 3][n];
        *(float4*)(out + (size_t)b * (NTOK * 96) + n * 96 + h * 32 + d0) = x4;
    }
}

extern "C" void kernel_launch(void* const* d_in, const int* in_sizes, int n_in,
                              void* d_out, int out_size, void* d_ws, size_t ws_size,
                              hipStream_t stream) {
    const float* qkv = (const float*)d_in[0];
    const float* w1  = (const float*)d_in[1];
    const float* b1  = (const float*)d_in[2];
    const float* w2  = (const float*)d_in[3];
    const float* b2  = (const float*)d_in[4];
    float* out = (float*)d_out;
    float* bias = (float*)d_ws;   // 3*64*64 floats = 48 KB

    bias_kernel<<<16, 256, 0, stream>>>(w1, b1, w2, b2, bias);
    attn_kernel<<<B_TOT * NHEAD, 256, 0, stream>>>(qkv, bias, out);
}

// Round 2
// 78.679 us; speedup vs baseline: 1.4645x; 1.4645x over previous
//
#include <hip/hip_runtime.h>

#define B_TOT 2048
#define NHEAD 3

typedef __attribute__((ext_vector_type(8))) short short8v;
typedef __attribute__((ext_vector_type(4))) float f32x4;

static __device__ __forceinline__ unsigned short f2bf(float x) {
    unsigned u = __builtin_bit_cast(unsigned, x);
    u += 0x7FFFu + ((u >> 16) & 1u);
    return (unsigned short)(u >> 16);
}
static __device__ __forceinline__ float bf2f(unsigned short s) {
    unsigned u = ((unsigned)s) << 16;
    return __builtin_bit_cast(float, u);
}

// ---------------------------------------------------------------------------
// Bias MLP precompute (unchanged from round 1, verified): bias[h][n][m]
// ---------------------------------------------------------------------------
__global__ __launch_bounds__(256) void bias_kernel(const float* __restrict__ w1,
                                                   const float* __restrict__ b1,
                                                   const float* __restrict__ w2,
                                                   const float* __restrict__ b2,
                                                   float* __restrict__ bias) {
    int t = blockIdx.x * 256 + threadIdx.x;   // 0..4095
    int n = t >> 6, m = t & 63;
    float d0 = (float)((n >> 3) - (m >> 3));
    float d1 = (float)((n & 7) - (m & 7));
    float r0 = (d0 > 0.f ? 1.f : (d0 < 0.f ? -1.f : 0.f)) * log1pf(fabsf(d0));
    float r1 = (d1 > 0.f ? 1.f : (d1 < 0.f ? -1.f : 0.f)) * log1pf(fabsf(d1));
    float a0 = 0.f, a1 = 0.f, a2 = 0.f;
    for (int j = 0; j < 256; j++) {
        float hd = fmaf(r0, w1[j], fmaf(r1, w1[256 + j], b1[j]));
        hd = fmaxf(hd, 0.f);
        a0 = fmaf(hd, w2[j * 3 + 0], a0);
        a1 = fmaf(hd, w2[j * 3 + 1], a1);
        a2 = fmaf(hd, w2[j * 3 + 2], a2);
    }
    bias[0 * 4096 + n * 64 + m] = a0 + b2[0];
    bias[1 * 4096 + n * 64 + m] = a1 + b2[1];
    bias[2 * 4096 + n * 64 + m] = a2 + b2[2];
}

// ---------------------------------------------------------------------------
// Main kernel: 1 wave = 1 (b,h) unit; 4 units/block (same h per block).
// conv (fp32 VALU, k in regs) -> S = O*V^T (MFMA bf16 hi/lo) + bias ->
// in-register softmax -> P via LDS -> X = P*V (MFMA) -> store.
// ---------------------------------------------------------------------------
__global__ __launch_bounds__(256, 3) void attn_kernel(const float* __restrict__ qkv,
                                                      const float* __restrict__ bias,
                                                      float* __restrict__ out) {
    // per-wave 9216B region: q [64][36] f32 -> O [64][36] f32 -> P [64][72] bf16
    __shared__ float smem[4][64 * 36];
    __shared__ float bias_s[64 * 66];

    const int t = threadIdx.x;
    const int w = t >> 6;
    const int lane = t & 63;
    const int h = blockIdx.x % 3;
    const int b = (blockIdx.x / 3) * 4 + w;

    // cooperative bias load (block-shared, same h for all 4 waves)
    #pragma unroll
    for (int i = 0; i < 16; i++) {
        int idx = t + 256 * i;
        bias_s[(idx >> 6) * 66 + (idx & 63)] = bias[h * 4096 + idx];
    }
    __syncthreads();

    float* Qs = smem[w];
    const float* base = qkv + (size_t)b * (64 * 288) + h * 32;
    const float scale = 0.17677669529663687f;  // 32^-0.5

    // ---- q -> LDS (scaled), coalesced float4 ----
    {
        const int nr = lane >> 3, d0 = (lane & 7) * 4;
        #pragma unroll
        for (int s = 0; s < 8; s++) {
            int n = 8 * s + nr;
            float4 q4 = *(const float4*)(base + n * 288 + d0);
            q4.x *= scale; q4.y *= scale; q4.z *= scale; q4.w *= scale;
            *(float4*)(Qs + n * 36 + d0) = q4;
        }
    }

    // ---- k column (channel dd) into 64 regs, rows rotated by 4*H2 so all
    // conv register indices are compile-time ----
    const int dd = lane & 31, H2 = lane >> 5;
    float kreg[64];
    #pragma unroll
    for (int t8 = 0; t8 < 8; t8++) {
        const int rb = ((t8 + 4 * H2) & 7) * 8;
        #pragma unroll
        for (int tx = 0; tx < 8; tx++)
            kreg[t8 * 8 + tx] = base[(rb + tx) * 288 + 96 + dd];
    }

    asm volatile("s_waitcnt lgkmcnt(0)" ::: "memory");

    // ---- stage 1: 8x8 cyclic conv, lane owns channel dd, rows y=4*H2+yi ----
    float acc[4][8];
    #pragma unroll
    for (int yi = 0; yi < 4; yi++)
        #pragma unroll
        for (int x = 0; x < 8; x++) acc[yi][x] = 0.f;

    #pragma unroll
    for (int u = 0; u < 8; u++) {
        float q8[8];
        #pragma unroll
        for (int v = 0; v < 8; v++) q8[v] = Qs[(u * 8 + v) * 36 + dd];
        #pragma unroll
        for (int yi = 0; yi < 4; yi++) {
            const int s = (yi - u) & 7;   // (4*H2+yi-u)&7 == (4*H2 + s)&7 -> kreg row s
            #pragma unroll
            for (int v = 0; v < 8; v++) {
                #pragma unroll
                for (int x = 0; x < 8; x++)
                    acc[yi][x] = fmaf(q8[v], kreg[s * 8 + ((x - v) & 7)], acc[yi][x]);
            }
        }
    }

    // ---- O into same LDS region (program order after all q reads; DS FIFO) ----
    #pragma unroll
    for (int yi = 0; yi < 4; yi++) {
        const int n = (4 * H2 + yi) * 8;
        #pragma unroll
        for (int x = 0; x < 8; x++)
            Qs[(n + x) * 36 + dd] = acc[yi][x];
    }
    asm volatile("s_waitcnt lgkmcnt(0)" ::: "memory");

    const int g = lane >> 4, c = lane & 15;

    // ---- A-frags of O (hi/lo bf16): row = 16*mt + c, k-chunk = 8*g ----
    short8v Oh[4], Ol[4];
    #pragma unroll
    for (int mt = 0; mt < 4; mt++) {
        const float* rp = Qs + (16 * mt + c) * 36 + 8 * g;
        float4 x0 = *(const float4*)rp;
        float4 x1 = *(const float4*)(rp + 4);
        float xs[8] = {x0.x, x0.y, x0.z, x0.w, x1.x, x1.y, x1.z, x1.w};
        #pragma unroll
        for (int j = 0; j < 8; j++) {
            unsigned short hb = f2bf(xs[j]);
            Oh[mt][j] = (short)hb;
            Ol[mt][j] = (short)f2bf(xs[j] - bf2f(hb));
        }
    }

    // ---- B-frags of V^T (hi/lo): element V[16*nt + c][8*g + j], from global ----
    short8v Vh[4], Vl[4];
    #pragma unroll
    for (int nt = 0; nt < 4; nt++) {
        const float* vp = base + (16 * nt + c) * 288 + 192 + 8 * g;
        float4 x0 = *(const float4*)vp;
        float4 x1 = *(const float4*)(vp + 4);
        float xs[8] = {x0.x, x0.y, x0.z, x0.w, x1.x, x1.y, x1.z, x1.w};
        #pragma unroll
        for (int j = 0; j < 8; j++) {
            unsigned short hb = f2bf(xs[j]);
            Vh[nt][j] = (short)hb;
            Vl[nt][j] = (short)f2bf(xs[j] - bf2f(hb));
        }
    }

    // ---- S = O * V^T via MFMA (3 products: hh + hl + lh ~= fp32) ----
    f32x4 S[4][4];
    #pragma unroll
    for (int mt = 0; mt < 4; mt++)
        #pragma unroll
        for (int nt = 0; nt < 4; nt++) {
            f32x4 a = {0.f, 0.f, 0.f, 0.f};
            a = __builtin_amdgcn_mfma_f32_16x16x32_bf16(Oh[mt], Vh[nt], a, 0, 0, 0);
            a = __builtin_amdgcn_mfma_f32_16x16x32_bf16(Oh[mt], Vl[nt], a, 0, 0, 0);
            a = __builtin_amdgcn_mfma_f32_16x16x32_bf16(Ol[mt], Vh[nt], a, 0, 0, 0);
            S[mt][nt] = a;
        }

    // ---- prefetch V for PV stage (raw f32, packed later) ----
    float vb[2][2][8];   // [kt][dt][j] = V[32*kt + 8*g + j][16*dt + c]
    #pragma unroll
    for (int kt = 0; kt < 2; kt++)
        #pragma unroll
        for (int dt = 0; dt < 2; dt++)
            #pragma unroll
            for (int j = 0; j < 8; j++)
                vb[kt][dt][j] = base[(32 * kt + 8 * g + j) * 288 + 192 + 16 * dt + c];

    // ---- bias add + softmax (rows n = 16*mt + 4*g + r; cols across nt, c-lanes) ----
    #pragma unroll
    for (int mt = 0; mt < 4; mt++)
        #pragma unroll
        for (int nt = 0; nt < 4; nt++)
            #pragma unroll
            for (int r = 0; r < 4; r++)
                S[mt][nt][r] += bias_s[(16 * mt + 4 * g + r) * 66 + 16 * nt + c];

    float inv[4][4];
    #pragma unroll
    for (int mt = 0; mt < 4; mt++) {
        #pragma unroll
        for (int r = 0; r < 4; r++) {
            float m0 = fmaxf(fmaxf(S[mt][0][r], S[mt][1][r]), fmaxf(S[mt][2][r], S[mt][3][r]));
            m0 = fmaxf(m0, __shfl_xor(m0, 1, 64));
            m0 = fmaxf(m0, __shfl_xor(m0, 2, 64));
            m0 = fmaxf(m0, __shfl_xor(m0, 4, 64));
            m0 = fmaxf(m0, __shfl_xor(m0, 8, 64));
            float s0 = 0.f;
            #pragma unroll
            for (int nt = 0; nt < 4; nt++) {
                float e = __expf(S[mt][nt][r] - m0);
                S[mt][nt][r] = e;
                s0 += e;
            }
            s0 += __shfl_xor(s0, 1, 64);
            s0 += __shfl_xor(s0, 2, 64);
            s0 += __shfl_xor(s0, 4, 64);
            s0 += __shfl_xor(s0, 8, 64);
            inv[mt][r] = 1.f / s0;
        }
    }

    // ---- P (unnormalized) -> LDS bf16 [64][72] (aliases O region; O consumed) ----
    unsigned short* Ps = (unsigned short*)Qs;
    #pragma unroll
    for (int mt = 0; mt < 4; mt++)
        #pragma unroll
        for (int nt = 0; nt < 4; nt++)
            #pragma unroll
            for (int r = 0; r < 4; r++)
                Ps[(16 * mt + 4 * g + r) * 72 + 16 * nt + c] = f2bf(S[mt][nt][r]);
    asm volatile("s_waitcnt lgkmcnt(0)" ::: "memory");

    // ---- P A-frags: row = 16*mt + c, k-chunk = 32*kt + 8*g ----
    short8v Pf[4][2];
    #pragma unroll
    for (int mt = 0; mt < 4; mt++)
        #pragma unroll
        for (int kt = 0; kt < 2; kt++)
            Pf[mt][kt] = *(const short8v*)(Ps + (16 * mt + c) * 72 + 32 * kt + 8 * g);

    // ---- V B-frags for PV (single bf16) ----
    short8v Vp[2][2];
    #pragma unroll
    for (int kt = 0; kt < 2; kt++)
        #pragma unroll
        for (int dt = 0; dt < 2; dt++)
            #pragma unroll
            for (int j = 0; j < 8; j++)
                Vp[kt][dt][j] = (short)f2bf(vb[kt][dt][j]);

    // ---- X = P * V via MFMA ----
    f32x4 X[4][2];
    #pragma unroll
    for (int mt = 0; mt < 4; mt++)
        #pragma unroll
        for (int dt = 0; dt < 2; dt++) {
            f32x4 a = {0.f, 0.f, 0.f, 0.f};
            a = __builtin_amdgcn_mfma_f32_16x16x32_bf16(Pf[mt][0], Vp[0][dt], a, 0, 0, 0);
            a = __builtin_amdgcn_mfma_f32_16x16x32_bf16(Pf[mt][1], Vp[1][dt], a, 0, 0, 0);
            X[mt][dt] = a;
        }

    // ---- normalize + store: out[b][n][h*32 + d] ----
    float* op = out + (size_t)b * (64 * 96) + h * 32;
    #pragma unroll
    for (int mt = 0; mt < 4; mt++)
        #pragma unroll
        for (int dt = 0; dt < 2; dt++)
            #pragma unroll
            for (int r = 0; r < 4; r++)
                op[(16 * mt + 4 * g + r) * 96 + 16 * dt + c] = X[mt][dt][r] * inv[mt][r];
}

extern "C" void kernel_launch(void* const* d_in, const int* in_sizes, int n_in,
                              void* d_out, int out_size, void* d_ws, size_t ws_size,
                              hipStream_t stream) {
    const float* qkv = (const float*)d_in[0];
    const float* w1  = (const float*)d_in[1];
    const float* b1  = (const float*)d_in[2];
    const float* w2  = (const float*)d_in[3];
    const float* b2  = (const float*)d_in[4];
    float* out = (float*)d_out;
    float* bias = (float*)d_ws;   // 3*64*64 floats = 48 KB

    bias_kernel<<<16, 256, 0, stream>>>(w1, b1, w2, b2, bias);
    attn_kernel<<<(B_TOT / 4) * NHEAD, 256, 0, stream>>>(qkv, bias, out);
}